// Round 1
// baseline (25.782 us; speedup 1.0000x reference)
//
#include <hip/hip_runtime.h>

// Problem: B=16 rows; per row, base = logits + noise; select top K=1024 of
// N=4096; forward output == hard * x (collapsed softmax cancels to <1 ulp).
#define BB 16
#define NN 4096
#define KK 1024
#define THREADS 1024
#define PT (NN / THREADS)        // 4 elements / thread (strided)
#define NWAVES (THREADS / 64)    // 16

// Monotonic float->uint key: larger key <=> larger float (no NaNs here).
__device__ __forceinline__ unsigned fkey(float f) {
    unsigned u = __float_as_uint(f);
    return (u & 0x80000000u) ? ~u : (u | 0x80000000u);
}

__global__ __launch_bounds__(THREADS) void gumbel_topk_mask(
    const float* __restrict__ x,
    const float* __restrict__ logits,
    const float* __restrict__ noise,
    float* __restrict__ out)
{
    __shared__ unsigned keys[NN];      // 16 KiB
    __shared__ int wsum[NWAVES];
    __shared__ int ibcast;
    __shared__ int ecnt[THREADS];      // tie-rank scan (cold path)
    __shared__ int epfx[THREADS];

    const int b    = blockIdx.x;
    const int t    = threadIdx.x;
    const int lane = t & 63;
    const int wid  = t >> 6;
    const size_t row = (size_t)b * NN;

    // ---- stage keys into LDS ----
    for (int i = t; i < NN; i += THREADS)
        keys[i] = fkey(logits[i] + noise[row + i]);
    __syncthreads();

    // ---- bitwise radix binary search for the K-th largest key ----
    // Invariant: count(key >= pfx) >= K. Final pfx == K-th largest key.
    unsigned pfx = 0u;
    for (int bit = 31; bit >= 0; --bit) {
        unsigned cand = pfx | (1u << bit);
        int cnt = 0;
        #pragma unroll
        for (int j = 0; j < PT; ++j)
            cnt += (keys[t + j * THREADS] >= cand) ? 1 : 0;
        #pragma unroll
        for (int off = 32; off > 0; off >>= 1)
            cnt += __shfl_down(cnt, off, 64);
        if (lane == 0) wsum[wid] = cnt;
        __syncthreads();
        if (t == 0) {
            int s = 0;
            for (int w = 0; w < NWAVES; ++w) s += wsum[w];
            ibcast = s;
        }
        __syncthreads();
        if (ibcast >= KK) pfx = cand;
        // (hazard-free: next wsum write is ordered after everyone's read of
        //  ibcast by the first __syncthreads of the next iteration)
    }
    const unsigned T = pfx;

    // ---- count strictly-greater and equal (packed 16:16, max 4096 each) ----
    int packed = 0;
    #pragma unroll
    for (int j = 0; j < PT; ++j) {
        unsigned k = keys[t + j * THREADS];
        packed += (k > T) ? 1 : 0;
        packed += (k == T) ? (1 << 16) : 0;
    }
    #pragma unroll
    for (int off = 32; off > 0; off >>= 1)
        packed += __shfl_down(packed, off, 64);
    if (lane == 0) wsum[wid] = packed;
    __syncthreads();
    if (t == 0) {
        int s = 0;
        for (int w = 0; w < NWAVES; ++w) s += wsum[w];
        ibcast = s;
    }
    __syncthreads();
    const int total_g = ibcast & 0xFFFF;
    const int total_e = ibcast >> 16;
    const int rem = KK - total_g;          // equals to accept, lowest index first
    // Invariants: 1 <= rem <= total_e.

    // ---- tie ranking (block-uniform cold path; ties are measure-zero) ----
    const bool need_rank = (rem < total_e);
    if (need_rank) {
        int c = 0;
        for (int j = 0; j < PT; ++j)
            c += (keys[t * PT + j] == T) ? 1 : 0;
        ecnt[t] = c;
        __syncthreads();
        if (t == 0) {
            int s = 0;
            for (int i = 0; i < THREADS; ++i) { epfx[i] = s; s += ecnt[i]; }
        }
        __syncthreads();
    }

    // ---- emit hard * x (coalesced strided) ----
    for (int j = 0; j < PT; ++j) {
        int n = t + j * THREADS;
        unsigned k = keys[n];
        bool sel = (k > T);
        if (!sel && k == T) {
            if (!need_rank) {
                sel = true;                 // rem == total_e: take all equals
            } else {
                int c = n / PT;
                int r = epfx[c];
                for (int m = c * PT; m < n; ++m) r += (keys[m] == T) ? 1 : 0;
                sel = (r < rem);
            }
        }
        out[row + n] = sel ? x[row + n] : 0.0f;
    }
}

extern "C" void kernel_launch(void* const* d_in, const int* in_sizes, int n_in,
                              void* d_out, int out_size, void* d_ws, size_t ws_size,
                              hipStream_t stream) {
    const float* x      = (const float*)d_in[0];   // [B, N]
    const float* logits = (const float*)d_in[1];   // [N]
    const float* noise  = (const float*)d_in[2];   // [B, N]
    float* out = (float*)d_out;                    // [B, N]
    (void)in_sizes; (void)n_in; (void)out_size; (void)d_ws; (void)ws_size;
    gumbel_topk_mask<<<BB, THREADS, 0, stream>>>(x, logits, noise, out);
}